// Round 9
// baseline (121.541 us; speedup 1.0000x reference)
//
#include <hip/hip_runtime.h>
#include <hip/hip_bf16.h>
#include <math.h>

// Problem: B=16, K=256, D=128, H=64
// DIAGNOSTIC ROUND: kB body repeated x8 (idempotent stores, memory-clobber
// fenced) so kB's dispatch exceeds the harness fillBuffer dispatches (~39us)
// and surfaces in the top-5 rocprof table with true steady-state counters.
// kB_true = kB_dispatch_dur / 8. Next round reverts the rep loop.

#define Bn 16
#define Kn 256
#define Dn 128
#define Hn 64
#define NBLK 2048   // kB grid: 8 x 16 x 16
#define KB_REPS 8

typedef float f32x2 __attribute__((ext_vector_type(2)));
typedef int   i32x2 __attribute__((ext_vector_type(2)));

// Trans-free fast GELU on 2 lanes of packed f32 (see R6/R8 notes).
__device__ __forceinline__ void gelu_dot2(f32x2 a, f32x2 c, f32x2 w, f32x2& acc) {
    f32x2 x  = a + c;
    f32x2 x2 = x * x;
    f32x2 t1 = __builtin_elementwise_fma(x2, (f32x2)(-863592.7f), (f32x2)(-19312322.0f));
    f32x2 u  = __builtin_elementwise_fma(x, t1, (f32x2)1064987473.0f);
    i32x2 iu = __builtin_convertvector(u, i32x2);
    f32x2 e  = __builtin_bit_cast(f32x2, iu);
    f32x2 d  = e + 1.0f;
    i32x2 id = __builtin_bit_cast(i32x2, d);
    i32x2 ir = 0x7EF311C3 - id;
    f32x2 r0 = __builtin_bit_cast(f32x2, ir);
    f32x2 q  = __builtin_elementwise_fma(-d, r0, (f32x2)2.0f);
    f32x2 r  = r0 * q;
    f32x2 g  = x * r;
    acc = __builtin_elementwise_fma(g, w, acc);
}

// ---------------- Kernel A: hi/hj precompute ----------------
__global__ __launch_bounds__(256) void kA(const float* __restrict__ particles,
                                          const float* __restrict__ W1,
                                          const float* __restrict__ b1,
                                          float* __restrict__ hi,
                                          float* __restrict__ hj) {
    __shared__ __align__(16) float w1a[Dn * Hn];
    __shared__ __align__(16) float w1b[Dn * Hn];
    __shared__ __align__(16) float ps[16][Dn];
    __shared__ __align__(16) float b1s[Hn];

    const int tid = threadIdx.x;
    const int row0 = blockIdx.x * 16;

    for (int idx = tid; idx < (Dn * Hn) / 4; idx += 256) {
        ((float4*)w1a)[idx] = ((const float4*)W1)[idx];
        ((float4*)w1b)[idx] = ((const float4*)(W1 + Dn * Hn))[idx];
    }
    for (int idx = tid; idx < (16 * Dn) / 4; idx += 256)
        ((float4*)&ps[0][0])[idx] = ((const float4*)(particles + row0 * Dn))[idx];
    if (tid < Hn / 4)
        ((float4*)b1s)[tid] = ((const float4*)b1)[tid];
    __syncthreads();

    const int r  = tid >> 4;
    const int h0 = (tid & 15) * 4;

    float4 ai = {0.f, 0.f, 0.f, 0.f};
    float4 aj = {0.f, 0.f, 0.f, 0.f};
#pragma unroll 8
    for (int d = 0; d < Dn; ++d) {
        const float p  = ps[r][d];
        const float4 wa = *(const float4*)&w1a[d * Hn + h0];
        const float4 wb = *(const float4*)&w1b[d * Hn + h0];
        ai.x = fmaf(p, wa.x, ai.x); ai.y = fmaf(p, wa.y, ai.y);
        ai.z = fmaf(p, wa.z, ai.z); ai.w = fmaf(p, wa.w, ai.w);
        aj.x = fmaf(p, wb.x, aj.x); aj.y = fmaf(p, wb.y, aj.y);
        aj.z = fmaf(p, wb.z, aj.z); aj.w = fmaf(p, wb.w, aj.w);
    }
    const float4 bb = *(const float4*)&b1s[h0];
    ai.x += bb.x; ai.y += bb.y; ai.z += bb.z; ai.w += bb.w;

    *(float4*)&hi[(row0 + r) * Hn + h0] = ai;
    *(float4*)&hj[(row0 + r) * Hn + h0] = aj;
}

// ---------------- Kernel B: main pairwise kernel (body x KB_REPS) ----------------
__global__ __launch_bounds__(256) void kB(const float* __restrict__ hi,
                                          const float* __restrict__ hj,
                                          const float* __restrict__ positions,
                                          const float* __restrict__ W2,
                                          const float* __restrict__ b2,
                                          float* __restrict__ out,
                                          float* __restrict__ partials) {
    __shared__ __align__(16) float shi[16][68];
    __shared__ __align__(16) float shj[32][68];
    __shared__ float pix[16], piy[16], pjx[32], pjy[32];
    __shared__ float wsum[4];

    const int jt = blockIdx.x, it = blockIdx.y, b = blockIdx.z;
    const int tid = threadIdx.x;

    {
        const int r = tid >> 4, c4 = (tid & 15) * 4;
        *(float4*)&shi[r][c4] = *(const float4*)&hi[((b * Kn) + it * 16 + r) * Hn + c4];
        *(float4*)&shj[r][c4]      = *(const float4*)&hj[((b * Kn) + jt * 32 + r) * Hn + c4];
        *(float4*)&shj[r + 16][c4] = *(const float4*)&hj[((b * Kn) + jt * 32 + r + 16) * Hn + c4];
    }
    if (tid < 16) {
        pix[tid] = positions[((b * Kn) + it * 16 + tid) * 2 + 0];
        piy[tid] = positions[((b * Kn) + it * 16 + tid) * 2 + 1];
    }
    if (tid < 32) {
        pjx[tid] = positions[((b * Kn) + jt * 32 + tid) * 2 + 0];
        pjy[tid] = positions[((b * Kn) + jt * 32 + tid) * 2 + 1];
    }
    const float bb = b2[0];
    __syncthreads();

    const int ti = tid >> 4, tj = tid & 15;
    const f32x2* __restrict__ W2v = (const f32x2*)W2;

#pragma unroll 1
    for (int rep = 0; rep < KB_REPS; ++rep) {
        asm volatile("" ::: "memory");   // force true re-execution each rep

        f32x2 accA0 = {0.f, 0.f}, accB0 = {0.f, 0.f};
        f32x2 accA1 = {0.f, 0.f}, accB1 = {0.f, 0.f};
#pragma unroll
        for (int h = 0; h < Hn; h += 4) {
            const float4 a  = *(const float4*)&shi[ti][h];
            const float4 c0 = *(const float4*)&shj[tj][h];
            const float4 c1 = *(const float4*)&shj[tj + 16][h];
            const f32x2 w0 = W2v[(h >> 1) + 0];
            const f32x2 w1 = W2v[(h >> 1) + 1];
            gelu_dot2((f32x2){a.x, a.y}, (f32x2){c0.x, c0.y}, w0, accA0);
            gelu_dot2((f32x2){a.z, a.w}, (f32x2){c0.z, c0.w}, w1, accB0);
            gelu_dot2((f32x2){a.x, a.y}, (f32x2){c1.x, c1.y}, w0, accA1);
            gelu_dot2((f32x2){a.z, a.w}, (f32x2){c1.z, c1.w}, w1, accB1);
        }
        const f32x2 s0 = accA0 + accB0;
        const f32x2 s1 = accA1 + accB1;
        const float sd0 = s0.x + s0.y + bb;
        const float sd1 = s1.x + s1.y + bb;

        const float dx0 = pix[ti] - pjx[tj],      dy0 = piy[ti] - pjy[tj];
        const float dx1 = pix[ti] - pjx[tj + 16], dy1 = piy[ti] - pjy[tj + 16];
        const float d20 = dx0 * dx0 + dy0 * dy0;
        const float d21 = dx1 * dx1 + dy1 * dy1;
        const float td0 = (d20 > 0.0f) ? sqrtf(d20) : 0.0f;
        const float td1 = (d21 > 0.0f) ? sqrtf(d21) : 0.0f;

        const int i = it * 16 + ti, j0 = jt * 32 + tj;
        out[((b * Kn) + i) * Kn + j0]      = sd0;
        out[((b * Kn) + i) * Kn + j0 + 16] = sd1;

        float v = (sd0 - td0) * (sd0 - td0) + (sd1 - td1) * (sd1 - td1);
#pragma unroll
        for (int off = 32; off > 0; off >>= 1) v += __shfl_down(v, off);
        if ((tid & 63) == 0) wsum[tid >> 6] = v;
        __syncthreads();
        if (tid == 0) {
            const int bid = (b * gridDim.y + it) * gridDim.x + jt;
            partials[bid] = (wsum[0] + wsum[1]) + (wsum[2] + wsum[3]);
        }
        __syncthreads();   // protect wsum (WAR across reps)
    }
}

// ---------------- Kernel C: final loss reduction (deterministic order) ----------------
__global__ __launch_bounds__(256) void kC(const float* __restrict__ partials,
                                          float* __restrict__ loss_out) {
    __shared__ float s[256];
    const int tid = threadIdx.x;
    const float4* p4 = (const float4*)partials;        // NBLK/4 = 512 float4
    float v = 0.0f;
#pragma unroll
    for (int k = 0; k < 2; ++k) {
        const float4 x = p4[tid + k * 256];
        v += (x.x + x.y) + (x.z + x.w);
    }
    s[tid] = v;
    __syncthreads();
    for (int off = 128; off > 0; off >>= 1) {
        if (tid < off) s[tid] += s[tid + off];
        __syncthreads();
    }
    if (tid == 0)
        loss_out[0] = s[0] * (1.0f / (float)(Bn * Kn * Kn));
}

extern "C" void kernel_launch(void* const* d_in, const int* in_sizes, int n_in,
                              void* d_out, int out_size, void* d_ws, size_t ws_size,
                              hipStream_t stream) {
    const float* particles = (const float*)d_in[0];
    const float* positions = (const float*)d_in[1];
    const float* W1        = (const float*)d_in[2];
    const float* b1        = (const float*)d_in[3];
    const float* W2        = (const float*)d_in[4];
    const float* b2        = (const float*)d_in[5];

    float* out = (float*)d_out;                       // [B*K*K] sd, then [1] loss
    float* ws  = (float*)d_ws;
    float* hi       = ws;                             // B*K*H floats
    float* hj       = ws + Bn * Kn * Hn;
    float* partials = ws + 2 * Bn * Kn * Hn;          // NBLK floats

    kA<<<dim3((Bn * Kn) / 16), dim3(256), 0, stream>>>(particles, W1, b1, hi, hj);
    kB<<<dim3(Kn / 32, Kn / 16, Bn), dim3(256), 0, stream>>>(hi, hj, positions, W2, b2,
                                                             out, partials);
    kC<<<dim3(1), dim3(256), 0, stream>>>(partials, out + (size_t)Bn * Kn * Kn);
}

// Round 10
// 31.183 us; speedup vs baseline: 3.8976x; 3.8976x over previous
//
#include <hip/hip_runtime.h>
#include <hip/hip_bf16.h>
#include <math.h>

// Problem: B=16, K=256, D=128, H=64
//   hi[b,k,h] = particles[b,k,:] @ W1[:D, h] + b1[h]
//   hj[b,k,h] = particles[b,k,:] @ W1[D:, h]
//   sd[b,i,j] = sum_h gelu(hi[b,i,h] + hj[b,j,h]) * W2[h] + b2
//   loss = mean((sd - true_dist)^2)
//
// R9 diagnostic (measured): kB_true = 16.5us, VALUBusy 81% -> compiler
// SCALARIZED the f32x2 math. This round forces v_pk_*_f32 via inline asm.
// Sign trick: rcp magic with sign bit baked in (0xFEF311C3 - bits) yields -r0;
// the uniform sign propagates to acc, folded out as sd = b2 - sum. No neg
// modifiers needed.

#define Bn 16
#define Kn 256
#define Dn 128
#define Hn 64
#define NBLK 2048   // kB grid: 8 x 16 x 16

typedef float        f32x2 __attribute__((ext_vector_type(2)));
typedef int          i32x2 __attribute__((ext_vector_type(2)));
typedef unsigned int u32x2 __attribute__((ext_vector_type(2)));

__device__ __forceinline__ f32x2 pk_add(f32x2 a, f32x2 b) {
    f32x2 d; asm("v_pk_add_f32 %0, %1, %2" : "=v"(d) : "v"(a), "v"(b)); return d;
}
__device__ __forceinline__ f32x2 pk_mul(f32x2 a, f32x2 b) {
    f32x2 d; asm("v_pk_mul_f32 %0, %1, %2" : "=v"(d) : "v"(a), "v"(b)); return d;
}
__device__ __forceinline__ f32x2 pk_fma(f32x2 a, f32x2 b, f32x2 c) {
    f32x2 d; asm("v_pk_fma_f32 %0, %1, %2, %3" : "=v"(d) : "v"(a), "v"(b), "v"(c)); return d;
}

struct GeluK {
    f32x2 c1, c0, bias, one, two;
};

// acc += (-gelu(a+c)) * w      [9 pk + 4 scalar issue slots per 2 elements]
__device__ __forceinline__ void gelu_dot2(f32x2 a, f32x2 c, f32x2 w, f32x2& acc,
                                          const GeluK& k) {
    f32x2 x  = pk_add(a, c);
    f32x2 x2 = pk_mul(x, x);
    f32x2 t1 = pk_fma(x2, k.c1, k.c0);                 // c1*x^2 + c0   (both <0)
    f32x2 u  = pk_fma(x, t1, k.bias);                  // Schraudolph exp2 arg
    i32x2 iu = __builtin_convertvector(u, i32x2);      // 2x v_cvt_i32_f32
    f32x2 e  = __builtin_bit_cast(f32x2, iu);          // ~2^t
    f32x2 d  = pk_add(e, k.one);                       // 1 + e^{-y}
    u32x2 id = __builtin_bit_cast(u32x2, d);
    u32x2 ir = (u32x2)0xFEF311C3u - id;                // bits of -1/d (sign baked in)
    f32x2 nr0 = __builtin_bit_cast(f32x2, ir);         // -r0
    f32x2 q  = pk_fma(d, nr0, k.two);                  // 2 - d*r0
    f32x2 m  = pk_mul(nr0, q);                         // -r  (refined -1/d)
    f32x2 g  = pk_mul(x, m);                           // -x*sigmoid
    acc = pk_fma(g, w, acc);                           // acc -= gelu*w
}

// ---------------- Kernel A: hi/hj precompute ----------------
__global__ __launch_bounds__(256) void kA(const float* __restrict__ particles,
                                          const float* __restrict__ W1,
                                          const float* __restrict__ b1,
                                          float* __restrict__ hi,
                                          float* __restrict__ hj) {
    __shared__ __align__(16) float w1a[Dn * Hn];
    __shared__ __align__(16) float w1b[Dn * Hn];
    __shared__ __align__(16) float ps[16][Dn];
    __shared__ __align__(16) float b1s[Hn];

    const int tid = threadIdx.x;
    const int row0 = blockIdx.x * 16;

    for (int idx = tid; idx < (Dn * Hn) / 4; idx += 256) {
        ((float4*)w1a)[idx] = ((const float4*)W1)[idx];
        ((float4*)w1b)[idx] = ((const float4*)(W1 + Dn * Hn))[idx];
    }
    for (int idx = tid; idx < (16 * Dn) / 4; idx += 256)
        ((float4*)&ps[0][0])[idx] = ((const float4*)(particles + row0 * Dn))[idx];
    if (tid < Hn / 4)
        ((float4*)b1s)[tid] = ((const float4*)b1)[tid];
    __syncthreads();

    const int r  = tid >> 4;
    const int h0 = (tid & 15) * 4;

    float4 ai = {0.f, 0.f, 0.f, 0.f};
    float4 aj = {0.f, 0.f, 0.f, 0.f};
#pragma unroll 8
    for (int d = 0; d < Dn; ++d) {
        const float p  = ps[r][d];
        const float4 wa = *(const float4*)&w1a[d * Hn + h0];
        const float4 wb = *(const float4*)&w1b[d * Hn + h0];
        ai.x = fmaf(p, wa.x, ai.x); ai.y = fmaf(p, wa.y, ai.y);
        ai.z = fmaf(p, wa.z, ai.z); ai.w = fmaf(p, wa.w, ai.w);
        aj.x = fmaf(p, wb.x, aj.x); aj.y = fmaf(p, wb.y, aj.y);
        aj.z = fmaf(p, wb.z, aj.z); aj.w = fmaf(p, wb.w, aj.w);
    }
    const float4 bb = *(const float4*)&b1s[h0];
    ai.x += bb.x; ai.y += bb.y; ai.z += bb.z; ai.w += bb.w;

    *(float4*)&hi[(row0 + r) * Hn + h0] = ai;
    *(float4*)&hj[(row0 + r) * Hn + h0] = aj;
}

// ---------------- Kernel B: main pairwise kernel ----------------
// grid (K/32, K/16, B) = (8,16,16), 256 threads; 2 outputs/thread.
__global__ __launch_bounds__(256) void kB(const float* __restrict__ hi,
                                          const float* __restrict__ hj,
                                          const float* __restrict__ positions,
                                          const float* __restrict__ W2,
                                          const float* __restrict__ b2,
                                          float* __restrict__ out,
                                          float* __restrict__ partials) {
    __shared__ __align__(16) float shi[16][68];
    __shared__ __align__(16) float shj[32][68];
    __shared__ float pix[16], piy[16], pjx[32], pjy[32];
    __shared__ float wsum[4];

    const int jt = blockIdx.x, it = blockIdx.y, b = blockIdx.z;
    const int tid = threadIdx.x;

    {
        const int r = tid >> 4, c4 = (tid & 15) * 4;
        *(float4*)&shi[r][c4] = *(const float4*)&hi[((b * Kn) + it * 16 + r) * Hn + c4];
        *(float4*)&shj[r][c4]      = *(const float4*)&hj[((b * Kn) + jt * 32 + r) * Hn + c4];
        *(float4*)&shj[r + 16][c4] = *(const float4*)&hj[((b * Kn) + jt * 32 + r + 16) * Hn + c4];
    }
    if (tid < 16) {
        pix[tid] = positions[((b * Kn) + it * 16 + tid) * 2 + 0];
        piy[tid] = positions[((b * Kn) + it * 16 + tid) * 2 + 1];
    }
    if (tid < 32) {
        pjx[tid] = positions[((b * Kn) + jt * 32 + tid) * 2 + 0];
        pjy[tid] = positions[((b * Kn) + jt * 32 + tid) * 2 + 1];
    }
    const float bb = b2[0];
    __syncthreads();

    const int ti = tid >> 4, tj = tid & 15;
    const f32x2* __restrict__ W2v = (const f32x2*)W2;   // uniform -> SGPR loads

    GeluK k;
    k.c1   = (f32x2)(-863592.7f);
    k.c0   = (f32x2)(-19312322.0f);
    k.bias = (f32x2)(1064987473.0f);
    k.one  = (f32x2)(1.0f);
    k.two  = (f32x2)(2.0f);

    f32x2 accA0 = {0.f, 0.f}, accB0 = {0.f, 0.f};
    f32x2 accA1 = {0.f, 0.f}, accB1 = {0.f, 0.f};
#pragma unroll
    for (int h = 0; h < Hn; h += 4) {
        const float4 a  = *(const float4*)&shi[ti][h];
        const float4 c0 = *(const float4*)&shj[tj][h];
        const float4 c1 = *(const float4*)&shj[tj + 16][h];
        const f32x2 w0 = W2v[(h >> 1) + 0];
        const f32x2 w1 = W2v[(h >> 1) + 1];
        gelu_dot2((f32x2){a.x, a.y}, (f32x2){c0.x, c0.y}, w0, accA0, k);
        gelu_dot2((f32x2){a.z, a.w}, (f32x2){c0.z, c0.w}, w1, accB0, k);
        gelu_dot2((f32x2){a.x, a.y}, (f32x2){c1.x, c1.y}, w0, accA1, k);
        gelu_dot2((f32x2){a.z, a.w}, (f32x2){c1.z, c1.w}, w1, accB1, k);
    }
    const f32x2 s0 = accA0 + accB0;          // holds -sum
    const f32x2 s1 = accA1 + accB1;
    const float sd0 = bb - (s0.x + s0.y);    // sign folded out here
    const float sd1 = bb - (s1.x + s1.y);

    const float dx0 = pix[ti] - pjx[tj],      dy0 = piy[ti] - pjy[tj];
    const float dx1 = pix[ti] - pjx[tj + 16], dy1 = piy[ti] - pjy[tj + 16];
    const float d20 = dx0 * dx0 + dy0 * dy0;
    const float d21 = dx1 * dx1 + dy1 * dy1;
    const float td0 = (d20 > 0.0f) ? sqrtf(d20) : 0.0f;
    const float td1 = (d21 > 0.0f) ? sqrtf(d21) : 0.0f;

    const int i = it * 16 + ti, j0 = jt * 32 + tj;
    out[((b * Kn) + i) * Kn + j0]      = sd0;
    out[((b * Kn) + i) * Kn + j0 + 16] = sd1;

    // deterministic block reduce of squared error
    float v = (sd0 - td0) * (sd0 - td0) + (sd1 - td1) * (sd1 - td1);
#pragma unroll
    for (int off = 32; off > 0; off >>= 1) v += __shfl_down(v, off);
    if ((tid & 63) == 0) wsum[tid >> 6] = v;
    __syncthreads();
    if (tid == 0) {
        const int bid = (b * gridDim.y + it) * gridDim.x + jt;
        partials[bid] = (wsum[0] + wsum[1]) + (wsum[2] + wsum[3]);
    }
}

// ---------------- Kernel C: final loss reduction (deterministic order) ----------------
__global__ __launch_bounds__(256) void kC(const float* __restrict__ partials,
                                          float* __restrict__ loss_out) {
    __shared__ float s[256];
    const int tid = threadIdx.x;
    const float4* p4 = (const float4*)partials;        // NBLK/4 = 512 float4
    float v = 0.0f;
#pragma unroll
    for (int k = 0; k < 2; ++k) {
        const float4 x = p4[tid + k * 256];
        v += (x.x + x.y) + (x.z + x.w);
    }
    s[tid] = v;
    __syncthreads();
    for (int off = 128; off > 0; off >>= 1) {
        if (tid < off) s[tid] += s[tid + off];
        __syncthreads();
    }
    if (tid == 0)
        loss_out[0] = s[0] * (1.0f / (float)(Bn * Kn * Kn));
}

extern "C" void kernel_launch(void* const* d_in, const int* in_sizes, int n_in,
                              void* d_out, int out_size, void* d_ws, size_t ws_size,
                              hipStream_t stream) {
    const float* particles = (const float*)d_in[0];
    const float* positions = (const float*)d_in[1];
    const float* W1        = (const float*)d_in[2];
    const float* b1        = (const float*)d_in[3];
    const float* W2        = (const float*)d_in[4];
    const float* b2        = (const float*)d_in[5];

    float* out = (float*)d_out;                       // [B*K*K] sd, then [1] loss
    float* ws  = (float*)d_ws;
    float* hi       = ws;                             // B*K*H floats
    float* hj       = ws + Bn * Kn * Hn;
    float* partials = ws + 2 * Bn * Kn * Hn;          // NBLK floats

    kA<<<dim3((Bn * Kn) / 16), dim3(256), 0, stream>>>(particles, W1, b1, hi, hj);
    kB<<<dim3(Kn / 32, Kn / 16, Bn), dim3(256), 0, stream>>>(hi, hj, positions, W2, b2,
                                                             out, partials);
    kC<<<dim3(1), dim3(256), 0, stream>>>(partials, out + (size_t)Bn * Kn * Kn);
}

// Round 11
// 27.837 us; speedup vs baseline: 4.3662x; 1.1202x over previous
//
#include <hip/hip_runtime.h>
#include <hip/hip_bf16.h>
#include <math.h>

// Problem: B=16, K=256, D=128, H=64
//   sd[b,i,j] = sum_h gelu(hi[b,i,h] + hj[b,j,h]) * W2[h] + b2,  loss = MSE vs dist
//
// R10 lesson (measured): v_pk_*_f32 = same FLOP rate as scalar f32 on CDNA4
// (157 TF peak = 1 fma/lane/cyc); packing only saves issue slots. kB is
// ALU-bound -> reduce op COUNT: 1.702-sigmoid gelu (9 ops/elem), W2 via LDS
// (kills s_load lgkm stalls), 4 outputs/thread (LDS reads 1.25 b128/output/iter).

#define Bn 16
#define Kn 256
#define Dn 128
#define Hn 64
#define NBLK 1024   // kB grid: 8 x 8 x 16

// gelu(x) ~= x * sigmoid(1.702 x); sigmoid via Schraudolph exp2 bit-trick +
// magic-rcp with 1 Newton step. 8 VALU ops (x computed by caller).
//   u = fma(x, -1.702/ln2 * 2^23, (127-0.0436)*2^23); e = bits->float(int(u))
//   d = 1+e; r ~ 1/d; acc += (x*r)*w
__device__ __forceinline__ void gelu_acc(float x, float w, float& acc) {
    float u  = fmaf(x, -20598733.0f, 1064987473.0f);
    int   iu = (int)u;                                   // u in (0, 2^31) for |x|<45
    float e  = __builtin_bit_cast(float, iu);
    float d  = e + 1.0f;
    int   ir = 0x7EF311C3 - __builtin_bit_cast(int, d);
    float r0 = __builtin_bit_cast(float, ir);
    float r  = r0 * fmaf(-d, r0, 2.0f);
    acc = fmaf(x * r, w, acc);
}

// ---------------- Kernel A: hi/hj precompute ----------------
__global__ __launch_bounds__(256) void kA(const float* __restrict__ particles,
                                          const float* __restrict__ W1,
                                          const float* __restrict__ b1,
                                          float* __restrict__ hi,
                                          float* __restrict__ hj) {
    __shared__ __align__(16) float w1a[Dn * Hn];
    __shared__ __align__(16) float w1b[Dn * Hn];
    __shared__ __align__(16) float ps[16][Dn];
    __shared__ __align__(16) float b1s[Hn];

    const int tid = threadIdx.x;
    const int row0 = blockIdx.x * 16;

    for (int idx = tid; idx < (Dn * Hn) / 4; idx += 256) {
        ((float4*)w1a)[idx] = ((const float4*)W1)[idx];
        ((float4*)w1b)[idx] = ((const float4*)(W1 + Dn * Hn))[idx];
    }
    for (int idx = tid; idx < (16 * Dn) / 4; idx += 256)
        ((float4*)&ps[0][0])[idx] = ((const float4*)(particles + row0 * Dn))[idx];
    if (tid < Hn / 4)
        ((float4*)b1s)[tid] = ((const float4*)b1)[tid];
    __syncthreads();

    const int r  = tid >> 4;
    const int h0 = (tid & 15) * 4;

    float4 ai = {0.f, 0.f, 0.f, 0.f};
    float4 aj = {0.f, 0.f, 0.f, 0.f};
#pragma unroll 8
    for (int d = 0; d < Dn; ++d) {
        const float p  = ps[r][d];
        const float4 wa = *(const float4*)&w1a[d * Hn + h0];
        const float4 wb = *(const float4*)&w1b[d * Hn + h0];
        ai.x = fmaf(p, wa.x, ai.x); ai.y = fmaf(p, wa.y, ai.y);
        ai.z = fmaf(p, wa.z, ai.z); ai.w = fmaf(p, wa.w, ai.w);
        aj.x = fmaf(p, wb.x, aj.x); aj.y = fmaf(p, wb.y, aj.y);
        aj.z = fmaf(p, wb.z, aj.z); aj.w = fmaf(p, wb.w, aj.w);
    }
    const float4 bb = *(const float4*)&b1s[h0];
    ai.x += bb.x; ai.y += bb.y; ai.z += bb.z; ai.w += bb.w;

    *(float4*)&hi[(row0 + r) * Hn + h0] = ai;
    *(float4*)&hj[(row0 + r) * Hn + h0] = aj;
}

// ---------------- Kernel B: 32x32 tile, 4 outputs/thread ----------------
// grid (K/32, K/32, B) = (8,8,16), 256 threads. Thread (ti=tid>>4, tj=tid&15)
// computes (i0,j0) (i0,j1) (i1,j0) (i1,j1), i1=i0+16, j1=j0+16.
__global__ __launch_bounds__(256) void kB(const float* __restrict__ hi,
                                          const float* __restrict__ hj,
                                          const float* __restrict__ positions,
                                          const float* __restrict__ W2,
                                          const float* __restrict__ b2,
                                          float* __restrict__ out,
                                          float* __restrict__ partials) {
    __shared__ __align__(16) float shi[32][68];
    __shared__ __align__(16) float shj[32][68];
    __shared__ __align__(16) float w2s[Hn];
    __shared__ float pix[32], piy[32], pjx[32], pjy[32];
    __shared__ float wsum[4];

    const int jt = blockIdx.x, it = blockIdx.y, b = blockIdx.z;
    const int tid = threadIdx.x;
    const int bi = b * Kn + it * 32;
    const int bj = b * Kn + jt * 32;

    // stage: 512 float4 each for shi/shj (2 per thread)
    for (int idx = tid; idx < 512; idx += 256) {
        const int rr = idx >> 4, c4 = (idx & 15) * 4;
        *(float4*)&shi[rr][c4] = *(const float4*)&hi[(bi + rr) * Hn + c4];
        *(float4*)&shj[rr][c4] = *(const float4*)&hj[(bj + rr) * Hn + c4];
    }
    if (tid < Hn / 4)
        ((float4*)w2s)[tid] = ((const float4*)W2)[tid];
    if (tid < 32) {
        pix[tid] = positions[(bi + tid) * 2 + 0];
        piy[tid] = positions[(bi + tid) * 2 + 1];
        pjx[tid] = positions[(bj + tid) * 2 + 0];
        pjy[tid] = positions[(bj + tid) * 2 + 1];
    }
    const float bb = b2[0];
    __syncthreads();

    const int ti = tid >> 4, tj = tid & 15;

    float acc00 = 0.f, acc01 = 0.f, acc10 = 0.f, acc11 = 0.f;
#pragma unroll
    for (int h = 0; h < Hn; h += 4) {
        const float4 a0 = *(const float4*)&shi[ti][h];
        const float4 a1 = *(const float4*)&shi[ti + 16][h];
        const float4 c0 = *(const float4*)&shj[tj][h];
        const float4 c1 = *(const float4*)&shj[tj + 16][h];
        const float4 w  = *(const float4*)&w2s[h];
        gelu_acc(a0.x + c0.x, w.x, acc00); gelu_acc(a0.y + c0.y, w.y, acc00);
        gelu_acc(a0.z + c0.z, w.z, acc00); gelu_acc(a0.w + c0.w, w.w, acc00);
        gelu_acc(a0.x + c1.x, w.x, acc01); gelu_acc(a0.y + c1.y, w.y, acc01);
        gelu_acc(a0.z + c1.z, w.z, acc01); gelu_acc(a0.w + c1.w, w.w, acc01);
        gelu_acc(a1.x + c0.x, w.x, acc10); gelu_acc(a1.y + c0.y, w.y, acc10);
        gelu_acc(a1.z + c0.z, w.z, acc10); gelu_acc(a1.w + c0.w, w.w, acc10);
        gelu_acc(a1.x + c1.x, w.x, acc11); gelu_acc(a1.y + c1.y, w.y, acc11);
        gelu_acc(a1.z + c1.z, w.z, acc11); gelu_acc(a1.w + c1.w, w.w, acc11);
    }
    const float sd00 = acc00 + bb, sd01 = acc01 + bb;
    const float sd10 = acc10 + bb, sd11 = acc11 + bb;

    const float xi0 = pix[ti], yi0 = piy[ti], xi1 = pix[ti + 16], yi1 = piy[ti + 16];
    const float xj0 = pjx[tj], yj0 = pjy[tj], xj1 = pjx[tj + 16], yj1 = pjy[tj + 16];
    const float d200 = (xi0-xj0)*(xi0-xj0) + (yi0-yj0)*(yi0-yj0);
    const float d201 = (xi0-xj1)*(xi0-xj1) + (yi0-yj1)*(yi0-yj1);
    const float d210 = (xi1-xj0)*(xi1-xj0) + (yi1-yj0)*(yi1-yj0);
    const float d211 = (xi1-xj1)*(xi1-xj1) + (yi1-yj1)*(yi1-yj1);
    const float td00 = (d200 > 0.f) ? sqrtf(d200) : 0.f;
    const float td01 = (d201 > 0.f) ? sqrtf(d201) : 0.f;
    const float td10 = (d210 > 0.f) ? sqrtf(d210) : 0.f;
    const float td11 = (d211 > 0.f) ? sqrtf(d211) : 0.f;

    const int i0 = it * 32 + ti, i1 = i0 + 16;
    const int j0 = jt * 32 + tj, j1 = j0 + 16;
    out[((b * Kn) + i0) * Kn + j0] = sd00;
    out[((b * Kn) + i0) * Kn + j1] = sd01;
    out[((b * Kn) + i1) * Kn + j0] = sd10;
    out[((b * Kn) + i1) * Kn + j1] = sd11;

    // deterministic block reduce of squared error (4 outputs)
    float v = (sd00 - td00) * (sd00 - td00) + (sd01 - td01) * (sd01 - td01)
            + (sd10 - td10) * (sd10 - td10) + (sd11 - td11) * (sd11 - td11);
#pragma unroll
    for (int off = 32; off > 0; off >>= 1) v += __shfl_down(v, off);
    if ((tid & 63) == 0) wsum[tid >> 6] = v;
    __syncthreads();
    if (tid == 0) {
        const int bid = (b * gridDim.y + it) * gridDim.x + jt;
        partials[bid] = (wsum[0] + wsum[1]) + (wsum[2] + wsum[3]);
    }
}

// ---------------- Kernel C: final loss reduction (deterministic order) ----------------
__global__ __launch_bounds__(256) void kC(const float* __restrict__ partials,
                                          float* __restrict__ loss_out) {
    __shared__ float s[256];
    const int tid = threadIdx.x;
    const float4* p4 = (const float4*)partials;        // NBLK/4 = 256 float4
    const float4 x = p4[tid];
    s[tid] = (x.x + x.y) + (x.z + x.w);
    __syncthreads();
    for (int off = 128; off > 0; off >>= 1) {
        if (tid < off) s[tid] += s[tid + off];
        __syncthreads();
    }
    if (tid == 0)
        loss_out[0] = s[0] * (1.0f / (float)(Bn * Kn * Kn));
}

extern "C" void kernel_launch(void* const* d_in, const int* in_sizes, int n_in,
                              void* d_out, int out_size, void* d_ws, size_t ws_size,
                              hipStream_t stream) {
    const float* particles = (const float*)d_in[0];
    const float* positions = (const float*)d_in[1];
    const float* W1        = (const float*)d_in[2];
    const float* b1        = (const float*)d_in[3];
    const float* W2        = (const float*)d_in[4];
    const float* b2        = (const float*)d_in[5];

    float* out = (float*)d_out;                       // [B*K*K] sd, then [1] loss
    float* ws  = (float*)d_ws;
    float* hi       = ws;                             // B*K*H floats
    float* hj       = ws + Bn * Kn * Hn;
    float* partials = ws + 2 * Bn * Kn * Hn;          // NBLK floats

    kA<<<dim3((Bn * Kn) / 16), dim3(256), 0, stream>>>(particles, W1, b1, hi, hj);
    kB<<<dim3(Kn / 32, Kn / 32, Bn), dim3(256), 0, stream>>>(hi, hj, positions, W2, b2,
                                                             out, partials);
    kC<<<dim3(1), dim3(256), 0, stream>>>(partials, out + (size_t)Bn * Kn * Kn);
}